// Round 4
// baseline (1689.696 us; speedup 1.0000x reference)
//
#include <hip/hip_runtime.h>

#define HW 4096
#define CCH 256

typedef __bf16 bf16x8 __attribute__((ext_vector_type(8)));
typedef float f32x4 __attribute__((ext_vector_type(4)));
typedef unsigned short u16;

__device__ __forceinline__ u16 f2b(float f) {
  union { float f; unsigned u; } v; v.f = f;
  unsigned r = v.u + 0x7fff + ((v.u >> 16) & 1);   // RNE
  return (u16)(r >> 16);
}

// ---------------- Kernel P: bf16 weight relayouts ----------------
__global__ __launch_bounds__(256) void kprep(
    const float* __restrict__ qkv_w, const float* __restrict__ out_w,
    const float* __restrict__ ca_w1, const float* __restrict__ ca_w2,
    u16* __restrict__ wqkvT, u16* __restrict__ woutT,
    u16* __restrict__ cw1t, u16* __restrict__ cw2t)
{
  int i = blockIdx.x * 256 + threadIdx.x;
  if (i < 768 * 256) wqkvT[i] = f2b(qkv_w[(i & 255) * 768 + (i >> 8)]);
  if (i < 256 * 256) woutT[i] = f2b(out_w[(i & 255) * 256 + (i >> 8)]);
  if (i < 64 * 256)  cw1t[i]  = f2b(ca_w1[(i & 255) * 64 + (i >> 8)]);
  if (i < 256 * 64)  cw2t[i]  = f2b(ca_w2[(i & 63) * 256 + (i >> 6)]);
}

// ---------------- Kernel B: fused CA-gate + windowed MHSA + out-proj ----------------
// block = 4 horizontally adjacent windows (full 128-B line ownership)
__global__ __launch_bounds__(256, 1) void kb_fused(
    const float* __restrict__ x, float* __restrict__ x2,
    const u16* __restrict__ wqkvT, const float* __restrict__ qkv_b,
    const u16* __restrict__ woutT, const float* __restrict__ out_b,
    const u16* __restrict__ cw1t, const float* __restrict__ ca_b1,
    const u16* __restrict__ cw2t, const float* __restrict__ ca_b2)
{
  __shared__ u16 sX[4 * 64 * 256];  // 4 windows, [tok][c] xor-swizzled  128 KB
  __shared__ u16 sQ[64 * 64];       // H -> Q -> P -> O (shared per window) 8 KB
  __shared__ u16 sK[64 * 64];       //                                      8 KB
  __shared__ u16 sVT[64 * 64];      // V^T [d][tok]                         8 KB

  const int tid = threadIdx.x;
  const int lane = tid & 63;
  const int wv = __builtin_amdgcn_readfirstlane(tid >> 6);
  const int l15 = lane & 15;
  const int lg = lane >> 4;

  const int wid = blockIdx.x;            // 512 blocks: b(32) x wr(8) x half(2)
  const int b = wid >> 4;
  const int rem = wid & 15;
  const int wr = rem >> 1;
  const int half = rem & 1;
  const float* ximg = x + (size_t)b * CCH * HW;
  float* oimg = x2 + (size_t)b * CCH * HW;

  // ---- stage 4 windows -> sX, fully coalesced (8 rows x 128 B per channel) ----
  {
    const int px32 = tid & 31;
    const int rowslot = tid >> 5;                       // 0..7
    const int gbase = (wr * 8 + rowslot) * 64 + half * 32 + px32;
    const int win = px32 >> 3;
    const int tok = rowslot * 8 + (px32 & 7);
    const int sw = (tok & 7) << 3;
    u16* dst = sX + win * 16384 + tok * 256;
    for (int c0 = 0; c0 < 256; c0 += 8) {
      u16 u[8];
      #pragma unroll
      for (int j = 0; j < 8; ++j) u[j] = f2b(ximg[(size_t)(c0 + j) * HW + gbase]);
      uint4 pk;
      pk.x = u[0] | ((unsigned)u[1] << 16); pk.y = u[2] | ((unsigned)u[3] << 16);
      pk.z = u[4] | ((unsigned)u[5] << 16); pk.w = u[6] | ((unsigned)u[7] << 16);
      *reinterpret_cast<uint4*>(&dst[c0 ^ sw]) = pk;
    }
  }
  __syncthreads();

  const int tokA = wv * 16 + l15;          // wave strip row within a window
  const int swA = (tokA & 7) << 3;

  for (int w = 0; w < 4; ++w) {
    u16* sXw = sX + w * 16384;
    const int pb = wr * 512 + (half * 4 + w) * 8;
    const int pixT = pb + (tokA >> 3) * 64 + (tokA & 7);

    // ---- channel-attention gate for window w (wave-private strips) ----
    f32x4 acc16[16];
    {
      // layer1: H = relu(X @ W1 + b1) on own strip rows (raw x from sXw)
      bf16x8 aXr[8];
      #pragma unroll
      for (int kb = 0; kb < 8; ++kb)
        aXr[kb] = *reinterpret_cast<const bf16x8*>(&sXw[tokA * 256 + ((kb * 32 + lg * 8) ^ swA)]);
      #pragma unroll
      for (int nt1 = 0; nt1 < 4; ++nt1) {
        f32x4 c1 = {0.f, 0.f, 0.f, 0.f};
        #pragma unroll
        for (int kb = 0; kb < 8; ++kb) {
          bf16x8 bw = *reinterpret_cast<const bf16x8*>(&cw1t[(nt1 * 16 + l15) * 256 + kb * 32 + lg * 8]);
          c1 = __builtin_amdgcn_mfma_f32_16x16x32_bf16(aXr[kb], bw, c1, 0, 0, 0);
        }
        float bias1 = ca_b1[nt1 * 16 + l15];
        #pragma unroll
        for (int r = 0; r < 4; ++r) {
          int tok = wv * 16 + lg * 4 + r;
          sQ[tok * 64 + ((nt1 * 16 + l15) ^ ((tok & 7) << 3))] = f2b(fmaxf(c1[r] + bias1, 0.f));
        }
      }
      // layer2 swapped (row = out-channel, col = strip token) + gate
      bf16x8 hB[2];
      #pragma unroll
      for (int kb = 0; kb < 2; ++kb)
        hB[kb] = *reinterpret_cast<const bf16x8*>(&sQ[tokA * 64 + ((kb * 32 + lg * 8) ^ swA)]);
      #pragma unroll
      for (int nt = 0; nt < 16; ++nt) {
        f32x4 a2 = {0.f, 0.f, 0.f, 0.f};
        #pragma unroll
        for (int kb = 0; kb < 2; ++kb) {
          bf16x8 w2a = *reinterpret_cast<const bf16x8*>(&cw2t[(nt * 16 + l15) * 64 + kb * 32 + lg * 8]);
          a2 = __builtin_amdgcn_mfma_f32_16x16x32_bf16(w2a, hB[kb], a2, 0, 0, 0);
        }
        #pragma unroll
        for (int r = 0; r < 4; ++r) {
          int n = nt * 16 + lg * 4 + r;
          float av = a2[r] + ca_b2[n];
          float xv = ximg[(size_t)n * HW + pixT];        // fp32 x, L2-hot
          float xg = xv / (1.f + __expf(-av));
          acc16[nt][r] = xg + out_b[n];
          sXw[tokA * 256 + (n ^ swA)] = f2b(xg);         // own strip rows
        }
      }
    }
    __syncthreads();

    // ---- hoist xg A-fragments (whole window) into registers ----
    bf16x8 A_all[32];
    #pragma unroll
    for (int t = 0; t < 4; ++t) {
      int arow = t * 16 + l15;
      int asw = (arow & 7) << 3;
      #pragma unroll
      for (int kb = 0; kb < 8; ++kb)
        A_all[t * 8 + kb] = *reinterpret_cast<const bf16x8*>(&sXw[arow * 256 + ((kb * 32 + lg * 8) ^ asw)]);
    }

    for (int h = 0; h < 4; ++h) {
      // ---- QKV: wave owns 3 col-tiles; B loaded once, A from regs ----
      #pragma unroll
      for (int ti = 0; ti < 3; ++ti) {
        int tau = wv * 3 + ti;
        int kind = tau >> 2, sub = tau & 3;
        int colbase = kind * 256 + h * 64 + sub * 16;
        const u16* wp = wqkvT + (size_t)(colbase + l15) * 256 + lg * 8;
        bf16x8 Bf[8];
        #pragma unroll
        for (int kb = 0; kb < 8; ++kb)
          Bf[kb] = *reinterpret_cast<const bf16x8*>(wp + kb * 32);
        float bias = qkv_b[colbase + l15];
        #pragma unroll
        for (int t = 0; t < 4; ++t) {
          f32x4 acc = {0.f, 0.f, 0.f, 0.f};
          #pragma unroll
          for (int kb = 0; kb < 8; ++kb)
            acc = __builtin_amdgcn_mfma_f32_16x16x32_bf16(A_all[t * 8 + kb], Bf[kb], acc, 0, 0, 0);
          #pragma unroll
          for (int r = 0; r < 4; ++r) {
            int tok = t * 16 + lg * 4 + r;
            u16 uv = f2b(acc[r] + bias);
            int d = sub * 16 + l15;
            int sw = (tok & 7) << 3;
            if (kind == 0)      sQ [tok * 64 + (d ^ sw)] = uv;
            else if (kind == 1) sK [tok * 64 + (d ^ sw)] = uv;
            else                sVT[d * 64 + (tok ^ ((d & 7) << 3))] = uv;
          }
        }
      }
      __syncthreads();

      // ---- S = Q @ K^T (strip rows) ----
      bf16x8 aQ[2];
      #pragma unroll
      for (int kb = 0; kb < 2; ++kb)
        aQ[kb] = *reinterpret_cast<const bf16x8*>(&sQ[tokA * 64 + ((kb * 32 + lg * 8) ^ swA)]);
      f32x4 s4[4];
      #pragma unroll
      for (int jt = 0; jt < 4; ++jt) {
        int krow = jt * 16 + l15;
        int swk = (krow & 7) << 3;
        f32x4 acc = {0.f, 0.f, 0.f, 0.f};
        #pragma unroll
        for (int kb = 0; kb < 2; ++kb) {
          bf16x8 bK = *reinterpret_cast<const bf16x8*>(&sK[krow * 64 + ((kb * 32 + lg * 8) ^ swk)]);
          acc = __builtin_amdgcn_mfma_f32_16x16x32_bf16(aQ[kb], bK, acc, 0, 0, 0);
        }
        s4[jt] = acc;
      }
      // ---- softmax per row; P overwrites own sQ strip ----
      #pragma unroll
      for (int r = 0; r < 4; ++r) {
        float m = fmaxf(fmaxf(s4[0][r], s4[1][r]), fmaxf(s4[2][r], s4[3][r]));
        #pragma unroll
        for (int off = 1; off < 16; off <<= 1) m = fmaxf(m, __shfl_xor(m, off));
        float e0 = __expf((s4[0][r] - m) * 0.125f);
        float e1 = __expf((s4[1][r] - m) * 0.125f);
        float e2 = __expf((s4[2][r] - m) * 0.125f);
        float e3 = __expf((s4[3][r] - m) * 0.125f);
        float sum = e0 + e1 + e2 + e3;
        #pragma unroll
        for (int off = 1; off < 16; off <<= 1) sum += __shfl_xor(sum, off);
        float is = 1.f / sum;
        int tok = wv * 16 + lg * 4 + r;
        int swp = (tok & 7) << 3;
        sQ[tok * 64 + ((     l15) ^ swp)] = f2b(e0 * is);
        sQ[tok * 64 + ((16 + l15) ^ swp)] = f2b(e1 * is);
        sQ[tok * 64 + ((32 + l15) ^ swp)] = f2b(e2 * is);
        sQ[tok * 64 + ((48 + l15) ^ swp)] = f2b(e3 * is);
      }
      // ---- PV: O^T = V^T @ P^T (strip-private) ----
      bf16x8 bP[2];
      #pragma unroll
      for (int kb = 0; kb < 2; ++kb)
        bP[kb] = *reinterpret_cast<const bf16x8*>(&sQ[tokA * 64 + ((kb * 32 + lg * 8) ^ swA)]);
      f32x4 o4[4];
      #pragma unroll
      for (int dt = 0; dt < 4; ++dt) {
        int drow = dt * 16 + l15;
        int swd = (drow & 7) << 3;
        f32x4 acc = {0.f, 0.f, 0.f, 0.f};
        #pragma unroll
        for (int kb = 0; kb < 2; ++kb) {
          bf16x8 aV = *reinterpret_cast<const bf16x8*>(&sVT[drow * 64 + ((kb * 32 + lg * 8) ^ swd)]);
          acc = __builtin_amdgcn_mfma_f32_16x16x32_bf16(aV, bP[kb], acc, 0, 0, 0);
        }
        o4[dt] = acc;
      }
      // O -> own sQ strip as [tok][d]
      #pragma unroll
      for (int dt = 0; dt < 4; ++dt) {
        int d0 = dt * 16 + lg * 4;
        uint2 pk;
        pk.x = f2b(o4[dt][0]) | ((unsigned)f2b(o4[dt][1]) << 16);
        pk.y = f2b(o4[dt][2]) | ((unsigned)f2b(o4[dt][3]) << 16);
        *reinterpret_cast<uint2*>(&sQ[tokA * 64 + (d0 ^ swA)]) = pk;
      }
      // read back as B-frag (own strip; same-wave RAW, lgkmcnt handles)
      bf16x8 bO[2];
      #pragma unroll
      for (int kb = 0; kb < 2; ++kb)
        bO[kb] = *reinterpret_cast<const bf16x8*>(&sQ[tokA * 64 + ((kb * 32 + lg * 8) ^ swA)]);
      __syncthreads();   // all shared reads for head h done; next head may overwrite

      // ---- out-proj partial: acc16 += Wout[:, h*64:(h+1)*64] slice ----
      #pragma unroll
      for (int nt = 0; nt < 16; ++nt) {
        const u16* wp = woutT + (size_t)(nt * 16 + l15) * 256 + h * 64 + lg * 8;
        #pragma unroll
        for (int kb = 0; kb < 2; ++kb) {
          bf16x8 wA = *reinterpret_cast<const bf16x8*>(wp + kb * 32);
          acc16[nt] = __builtin_amdgcn_mfma_f32_16x16x32_bf16(wA, bO[kb], acc16[nt], 0, 0, 0);
        }
      }
    }

    // ---- store window w: x2 = xg + o (L2 merges sectors across w-iterations) ----
    #pragma unroll
    for (int nt = 0; nt < 16; ++nt) {
      #pragma unroll
      for (int r = 0; r < 4; ++r) {
        int n = nt * 16 + lg * 4 + r;
        oimg[(size_t)n * HW + pixT] = acc16[nt][r];
      }
    }
  }
}

// ---------------- Kernel C: grouped conv1 + BN + ReLU (quarter tiles) ----------------
__global__ __launch_bounds__(256) void kc_conv1(
    const float* __restrict__ x2, const float* __restrict__ w1, const float* __restrict__ b1,
    const float* __restrict__ g1, const float* __restrict__ bb1,
    const float* __restrict__ m1, const float* __restrict__ v1,
    float* __restrict__ y1)
{
  __shared__ float sin_[4 * 22 * 72];
  int wid = blockIdx.x;
  int b = wid >> 8, rem = wid & 255, j = rem >> 2, qt = rem & 3;
  const float* img = x2 + (size_t)b * CCH * HW;
  for (int idx = threadIdx.x; idx < 4 * 22 * 70; idx += 256) {
    int i = idx / 1540, r2 = idx - i * 1540;
    int yy = r2 / 70, xx = r2 - yy * 70;
    int ih = qt * 16 + yy - 3, iw = xx - 3;
    float v = 0.f;
    if (ih >= 0 && ih < 64 && iw >= 0 && iw < 64)
      v = img[(size_t)(i * 64 + j) * HW + ih * 64 + iw];
    sin_[(i * 22 + yy) * 72 + xx] = v;
  }
  __syncthreads();

  float inv = g1[j] / sqrtf(v1[j] + 1e-5f);
  float shf = bb1[j] - m1[j] * inv;
  float bia = b1[j];
  float* yo = y1 + ((size_t)b * 64 + j) * HW + qt * 16 * 64;
  const float* wbase = w1 + j * 4 * 49;

  int y = threadIdx.x >> 4, x4 = (threadIdx.x & 15) * 4;
  float a0 = 0.f, a1 = 0.f, a2 = 0.f, a3 = 0.f;
  for (int i = 0; i < 4; ++i) {
    #pragma unroll
    for (int ky = 0; ky < 7; ++ky) {
      const float* row = sin_ + (i * 22 + y + ky) * 72 + x4;
      float v[10];
      #pragma unroll
      for (int q = 0; q < 10; ++q) v[q] = row[q];
      const float* wr = wbase + (i * 7 + ky) * 7;
      #pragma unroll
      for (int kx = 0; kx < 7; ++kx) {
        float wvv = wr[kx];
        a0 += v[kx] * wvv; a1 += v[kx+1] * wvv;
        a2 += v[kx+2] * wvv; a3 += v[kx+3] * wvv;
      }
    }
  }
  float4 r4;
  r4.x = fmaxf((a0 + bia) * inv + shf, 0.f);
  r4.y = fmaxf((a1 + bia) * inv + shf, 0.f);
  r4.z = fmaxf((a2 + bia) * inv + shf, 0.f);
  r4.w = fmaxf((a3 + bia) * inv + shf, 0.f);
  *reinterpret_cast<float4*>(yo + y * 64 + x4) = r4;
}

// ---------------- Kernel D: grouped conv2 + BN + sigmoid gate * shuffled x2 ----------------
__global__ __launch_bounds__(256) void kd_conv2(
    const float* __restrict__ y1, const float* __restrict__ x2,
    const float* __restrict__ w2, const float* __restrict__ b2,
    const float* __restrict__ g2, const float* __restrict__ bb2,
    const float* __restrict__ m2, const float* __restrict__ v2,
    float* __restrict__ out)
{
  __shared__ float sin_[70 * 72];
  int wid = blockIdx.x;
  int b = wid >> 6, g = wid & 63;
  const float* yin = y1 + ((size_t)b * 64 + g) * HW;
  for (int idx = threadIdx.x; idx < 70 * 70; idx += 256) {
    int yy = idx / 70, xx = idx - yy * 70;
    int ih = yy - 3, iw = xx - 3;
    float v = 0.f;
    if (ih >= 0 && ih < 64 && iw >= 0 && iw < 64) v = yin[ih * 64 + iw];
    sin_[yy * 72 + xx] = v;
  }
  __syncthreads();

  float inv[4], shf[4], bia[4];
  #pragma unroll
  for (int i = 0; i < 4; ++i) {
    int n = 4 * g + i;
    float sc = g2[n] / sqrtf(v2[n] + 1e-5f);
    inv[i] = sc; shf[i] = bb2[n] - m2[n] * sc; bia[i] = b2[n];
  }
  const float* wb = w2 + 4 * g * 49;

  for (int it = 0; it < 4; ++it) {
    int s = it * 256 + threadIdx.x;
    int y = s >> 4, x4 = (s & 15) * 4;
    float acc[4][4] = {};
    #pragma unroll
    for (int ky = 0; ky < 7; ++ky) {
      const float* row = sin_ + (y + ky) * 72 + x4;
      float v[10];
      #pragma unroll
      for (int q = 0; q < 10; ++q) v[q] = row[q];
      #pragma unroll
      for (int i = 0; i < 4; ++i) {
        const float* wr = wb + i * 49 + ky * 7;
        #pragma unroll
        for (int kx = 0; kx < 7; ++kx) {
          float wvv = wr[kx];
          acc[i][0] += v[kx] * wvv; acc[i][1] += v[kx+1] * wvv;
          acc[i][2] += v[kx+2] * wvv; acc[i][3] += v[kx+3] * wvv;
        }
      }
    }
    int po = y * 64 + x4;
    #pragma unroll
    for (int i = 0; i < 4; ++i) {
      int n = 4 * g + i;
      const float* xs = x2 + ((size_t)b * 256 + (i * 64 + g)) * HW + po;
      float* op = out + ((size_t)b * 256 + n) * HW + po;
      #pragma unroll
      for (int px = 0; px < 4; ++px) {
        float yv = (acc[i][px] + bia[i]) * inv[i] + shf[i];
        op[px] = xs[px] / (1.f + __expf(-yv));
      }
    }
  }
}

extern "C" void kernel_launch(void* const* d_in, const int* in_sizes, int n_in,
                              void* d_out, int out_size, void* d_ws, size_t ws_size,
                              hipStream_t stream) {
  const float* x     = (const float*)d_in[0];
  const float* qkv_w = (const float*)d_in[1];
  const float* qkv_b = (const float*)d_in[2];
  const float* out_w = (const float*)d_in[3];
  const float* out_b = (const float*)d_in[4];
  const float* ca_w1 = (const float*)d_in[5];
  const float* ca_b1 = (const float*)d_in[6];
  const float* ca_w2 = (const float*)d_in[7];
  const float* ca_b2 = (const float*)d_in[8];
  const float* sa_w1 = (const float*)d_in[9];
  const float* sa_b1 = (const float*)d_in[10];
  const float* bn1_g = (const float*)d_in[11];
  const float* bn1_b = (const float*)d_in[12];
  const float* bn1_m = (const float*)d_in[13];
  const float* bn1_v = (const float*)d_in[14];
  const float* sa_w2 = (const float*)d_in[15];
  const float* sa_b2 = (const float*)d_in[16];
  const float* bn2_g = (const float*)d_in[17];
  const float* bn2_b = (const float*)d_in[18];
  const float* bn2_m = (const float*)d_in[19];
  const float* bn2_v = (const float*)d_in[20];

  float* outp = (float*)d_out;
  float* x2 = (float*)d_ws;                         // xg + attn out
  float* y1 = x2 + (size_t)32 * 256 * 4096;         // conv1 output (b,64,64,64)

  // stash bf16 weight relayouts at the head of d_out (overwritten by kd at the end)
  u16* wqkvT = (u16*)d_out;                         // 196608
  u16* woutT = wqkvT + 768 * 256;                   // 65536
  u16* cw1t  = woutT + 256 * 256;                   // 16384
  u16* cw2t  = cw1t + 64 * 256;                     // 16384

  kprep   <<<768,  256, 0, stream>>>(qkv_w, out_w, ca_w1, ca_w2, wqkvT, woutT, cw1t, cw2t);
  kb_fused<<<512,  256, 0, stream>>>(x, x2, wqkvT, qkv_b, woutT, out_b, cw1t, ca_b1, cw2t, ca_b2);
  kc_conv1<<<8192, 256, 0, stream>>>(x2, sa_w1, sa_b1, bn1_g, bn1_b, bn1_m, bn1_v, y1);
  kd_conv2<<<2048, 256, 0, stream>>>(y1, x2, sa_w2, sa_b2, bn2_g, bn2_b, bn2_m, bn2_v, outp);
}

// Round 5
// 975.154 us; speedup vs baseline: 1.7327x; 1.7327x over previous
//
#include <hip/hip_runtime.h>

#define HW 4096
#define CCH 256

typedef __bf16 bf16x8 __attribute__((ext_vector_type(8)));
typedef float f32x4 __attribute__((ext_vector_type(4)));
typedef unsigned short u16;

__device__ __forceinline__ u16 f2b(float f) {
  union { float f; unsigned u; } v; v.f = f;
  unsigned r = v.u + 0x7fff + ((v.u >> 16) & 1);   // RNE
  return (u16)(r >> 16);
}

// ---------------- Kernel P: bf16 weight relayouts ----------------
__global__ __launch_bounds__(256) void kprep(
    const float* __restrict__ qkv_w, const float* __restrict__ out_w,
    const float* __restrict__ ca_w1, const float* __restrict__ ca_w2,
    u16* __restrict__ wqkvT, u16* __restrict__ woutT,
    u16* __restrict__ cw1t, u16* __restrict__ cw2t)
{
  int i = blockIdx.x * 256 + threadIdx.x;
  if (i < 768 * 256) wqkvT[i] = f2b(qkv_w[(i & 255) * 768 + (i >> 8)]);
  if (i < 256 * 256) woutT[i] = f2b(out_w[(i & 255) * 256 + (i >> 8)]);
  if (i < 64 * 256)  cw1t[i]  = f2b(ca_w1[(i & 255) * 64 + (i >> 8)]);
  if (i < 256 * 64)  cw2t[i]  = f2b(ca_w2[(i & 63) * 256 + (i >> 6)]);
}

// ---------------- Kernel B: fused CA-gate + windowed MHSA + out-proj ----------------
// one window per block (r3 structure); XCD-chunked swizzle so the 4 windows
// sharing each 128-B line run on the same XCD (L2 sector merging)
__global__ __launch_bounds__(256, 2) void kb_fused(
    const float* __restrict__ x, float* __restrict__ x2,
    const u16* __restrict__ wqkvT, const float* __restrict__ qkv_b,
    const u16* __restrict__ woutT, const float* __restrict__ out_b,
    const u16* __restrict__ cw1t, const float* __restrict__ ca_b1,
    const u16* __restrict__ cw2t, const float* __restrict__ ca_b2)
{
  __shared__ u16 sX[64 * 256];   // x -> xg -> O (per-head 64-col slices)   32 KB
  __shared__ u16 sQ[64 * 64];    // H -> Q -> P                              8 KB
  __shared__ u16 sK[64 * 64];    //                                          8 KB
  __shared__ u16 sVT[64 * 64];   // V^T [d][tok]                             8 KB

  const int tid = threadIdx.x;
  const int lane = tid & 63;
  const int wv = __builtin_amdgcn_readfirstlane(tid >> 6);
  const int l15 = lane & 15;
  const int lg = lane >> 4;

  // XCD-chunked window assignment: XCD k owns linear windows [k*256,(k+1)*256)
  const int bid = blockIdx.x;
  const int wid = (bid & 7) * 256 + (bid >> 3);
  const int b = wid >> 6, wrem = wid & 63;
  const int pbase = (wrem >> 3) * (8 * 64) + (wrem & 7) * 8;
  const float* ximg = x + (size_t)b * CCH * HW;
  float* oimg = x2 + (size_t)b * CCH * HW;

  const int tokA = wv * 16 + l15;          // wave strip row
  const int swA = (tokA & 7) << 3;
  const int pixT = pbase + (tokA >> 3) * 64 + (tokA & 7);

  // ---- stage raw x -> sX (bf16, [tok][c] xor-swizzled) ----
  {
    const int tok = lane;
    const int pix = pbase + (tok >> 3) * 64 + (tok & 7);
    const int sw = (tok & 7) << 3;
    for (int p = 0; p < 8; ++p) {
      int c0 = (p * 4 + wv) * 8;
      u16 u[8];
      #pragma unroll
      for (int j = 0; j < 8; ++j) u[j] = f2b(ximg[(size_t)(c0 + j) * HW + pix]);
      uint4 pk;
      pk.x = u[0] | ((unsigned)u[1] << 16); pk.y = u[2] | ((unsigned)u[3] << 16);
      pk.z = u[4] | ((unsigned)u[5] << 16); pk.w = u[6] | ((unsigned)u[7] << 16);
      *reinterpret_cast<uint4*>(&sX[tok * 256 + (c0 ^ sw)]) = pk;
    }
  }
  __syncthreads();

  // ---- channel-attention gating (per wave, strip-private) ----
  f32x4 acc_out[16];   // (row = out-channel, col = strip token); init xg + out_b
  {
    bf16x8 aXr[8];
    #pragma unroll
    for (int kb = 0; kb < 8; ++kb)
      aXr[kb] = *reinterpret_cast<const bf16x8*>(&sX[tokA * 256 + ((kb * 32 + lg * 8) ^ swA)]);
    #pragma unroll
    for (int nt1 = 0; nt1 < 4; ++nt1) {
      f32x4 c1 = {0.f, 0.f, 0.f, 0.f};
      #pragma unroll
      for (int kb = 0; kb < 8; ++kb) {
        bf16x8 bw = *reinterpret_cast<const bf16x8*>(&cw1t[(nt1 * 16 + l15) * 256 + kb * 32 + lg * 8]);
        c1 = __builtin_amdgcn_mfma_f32_16x16x32_bf16(aXr[kb], bw, c1, 0, 0, 0);
      }
      float bias1 = ca_b1[nt1 * 16 + l15];
      #pragma unroll
      for (int r = 0; r < 4; ++r) {
        int tok = wv * 16 + lg * 4 + r;
        sQ[tok * 64 + ((nt1 * 16 + l15) ^ ((tok & 7) << 3))] = f2b(fmaxf(c1[r] + bias1, 0.f));
      }
    }
    bf16x8 hB[2];
    #pragma unroll
    for (int kb = 0; kb < 2; ++kb)
      hB[kb] = *reinterpret_cast<const bf16x8*>(&sQ[tokA * 64 + ((kb * 32 + lg * 8) ^ swA)]);
    #pragma unroll
    for (int nt = 0; nt < 16; ++nt) {
      f32x4 a2 = {0.f, 0.f, 0.f, 0.f};
      #pragma unroll
      for (int kb = 0; kb < 2; ++kb) {
        bf16x8 w2a = *reinterpret_cast<const bf16x8*>(&cw2t[(nt * 16 + l15) * 64 + kb * 32 + lg * 8]);
        a2 = __builtin_amdgcn_mfma_f32_16x16x32_bf16(w2a, hB[kb], a2, 0, 0, 0);
      }
      #pragma unroll
      for (int r = 0; r < 4; ++r) {
        int n = nt * 16 + lg * 4 + r;
        float av = a2[r] + ca_b2[n];
        float xv = ximg[(size_t)n * HW + pixT];           // fp32 x (L2 hot on own XCD)
        float xg = xv / (1.f + __expf(-av));
        acc_out[nt][r] = xg + out_b[n];
        sX[tokA * 256 + (n ^ swA)] = f2b(xg);             // overwrite own strip row
      }
    }
  }
  __syncthreads();

  // ---- hoist all QKV A-fragments (xg window) into registers ----
  bf16x8 A_all[32];
  #pragma unroll
  for (int t = 0; t < 4; ++t) {
    int arow = t * 16 + l15;
    int asw = (arow & 7) << 3;
    #pragma unroll
    for (int kb = 0; kb < 8; ++kb)
      A_all[t * 8 + kb] = *reinterpret_cast<const bf16x8*>(&sX[arow * 256 + ((kb * 32 + lg * 8) ^ asw)]);
  }
  // sX is now dead as xg storage; O_h slices get written into it per head.

  for (int h = 0; h < 4; ++h) {
    // ---------- QKV: wave owns 3 col-tiles; B loaded once, A from regs ----------
    #pragma unroll
    for (int ti = 0; ti < 3; ++ti) {
      int tau = wv * 3 + ti;
      int kind = tau >> 2, sub = tau & 3;
      int colbase = kind * 256 + h * 64 + sub * 16;
      const u16* wp = wqkvT + (size_t)(colbase + l15) * 256 + lg * 8;
      bf16x8 Bf[8];
      #pragma unroll
      for (int kb = 0; kb < 8; ++kb)
        Bf[kb] = *reinterpret_cast<const bf16x8*>(wp + kb * 32);
      float bias = qkv_b[colbase + l15];
      #pragma unroll
      for (int t = 0; t < 4; ++t) {
        f32x4 acc = {0.f, 0.f, 0.f, 0.f};
        #pragma unroll
        for (int kb = 0; kb < 8; ++kb)
          acc = __builtin_amdgcn_mfma_f32_16x16x32_bf16(A_all[t * 8 + kb], Bf[kb], acc, 0, 0, 0);
        #pragma unroll
        for (int r = 0; r < 4; ++r) {
          int tok = t * 16 + lg * 4 + r;
          u16 uv = f2b(acc[r] + bias);
          int d = sub * 16 + l15;
          int sw = (tok & 7) << 3;
          if (kind == 0)      sQ [tok * 64 + (d ^ sw)] = uv;
          else if (kind == 1) sK [tok * 64 + (d ^ sw)] = uv;
          else                sVT[d * 64 + (tok ^ ((d & 7) << 3))] = uv;
        }
      }
    }
    __syncthreads();

    // ---------- scores S = Q @ K^T (strip rows) ----------
    bf16x8 aQ[2];
    #pragma unroll
    for (int kb = 0; kb < 2; ++kb)
      aQ[kb] = *reinterpret_cast<const bf16x8*>(&sQ[tokA * 64 + ((kb * 32 + lg * 8) ^ swA)]);
    f32x4 s4[4];
    #pragma unroll
    for (int jt = 0; jt < 4; ++jt) {
      int krow = jt * 16 + l15;
      int swk = (krow & 7) << 3;
      f32x4 acc = {0.f, 0.f, 0.f, 0.f};
      #pragma unroll
      for (int kb = 0; kb < 2; ++kb) {
        bf16x8 bK = *reinterpret_cast<const bf16x8*>(&sK[krow * 64 + ((kb * 32 + lg * 8) ^ swk)]);
        acc = __builtin_amdgcn_mfma_f32_16x16x32_bf16(aQ[kb], bK, acc, 0, 0, 0);
      }
      s4[jt] = acc;
    }
    // ---------- softmax per row, P overwrites own sQ strip ----------
    #pragma unroll
    for (int r = 0; r < 4; ++r) {
      float m = fmaxf(fmaxf(s4[0][r], s4[1][r]), fmaxf(s4[2][r], s4[3][r]));
      #pragma unroll
      for (int off = 1; off < 16; off <<= 1) m = fmaxf(m, __shfl_xor(m, off));
      float e0 = __expf((s4[0][r] - m) * 0.125f);
      float e1 = __expf((s4[1][r] - m) * 0.125f);
      float e2 = __expf((s4[2][r] - m) * 0.125f);
      float e3 = __expf((s4[3][r] - m) * 0.125f);
      float sum = e0 + e1 + e2 + e3;
      #pragma unroll
      for (int off = 1; off < 16; off <<= 1) sum += __shfl_xor(sum, off);
      float is = 1.f / sum;
      int tok = wv * 16 + lg * 4 + r;
      int swp = (tok & 7) << 3;
      sQ[tok * 64 + ((     l15) ^ swp)] = f2b(e0 * is);
      sQ[tok * 64 + ((16 + l15) ^ swp)] = f2b(e1 * is);
      sQ[tok * 64 + ((32 + l15) ^ swp)] = f2b(e2 * is);
      sQ[tok * 64 + ((48 + l15) ^ swp)] = f2b(e3 * is);
    }
    // ---------- PV: O^T = V^T @ P^T (strip-private) ----------
    bf16x8 bP[2];
    #pragma unroll
    for (int kb = 0; kb < 2; ++kb)
      bP[kb] = *reinterpret_cast<const bf16x8*>(&sQ[tokA * 64 + ((kb * 32 + lg * 8) ^ swA)]);
    f32x4 o4[4];
    #pragma unroll
    for (int dt = 0; dt < 4; ++dt) {
      int drow = dt * 16 + l15;
      int swd = (drow & 7) << 3;
      f32x4 acc = {0.f, 0.f, 0.f, 0.f};
      #pragma unroll
      for (int kb = 0; kb < 2; ++kb) {
        bf16x8 aV = *reinterpret_cast<const bf16x8*>(&sVT[drow * 64 + ((kb * 32 + lg * 8) ^ swd)]);
        acc = __builtin_amdgcn_mfma_f32_16x16x32_bf16(aV, bP[kb], acc, 0, 0, 0);
      }
      o4[dt] = acc;
    }
    // O_h -> sX[tok][h*64 + d]  (own strip rows)
    #pragma unroll
    for (int dt = 0; dt < 4; ++dt) {
      int d0 = h * 64 + dt * 16 + lg * 4;
      uint2 pk;
      pk.x = f2b(o4[dt][0]) | ((unsigned)f2b(o4[dt][1]) << 16);
      pk.y = f2b(o4[dt][2]) | ((unsigned)f2b(o4[dt][3]) << 16);
      *reinterpret_cast<uint2*>(&sX[tokA * 256 + (d0 ^ swA)]) = pk;
    }
    __syncthreads();
  }

  // ---------- out-proj (K=256, swapped operands) + store x2 = xg + o ----------
  bf16x8 oB[8];
  #pragma unroll
  for (int kb = 0; kb < 8; ++kb)
    oB[kb] = *reinterpret_cast<const bf16x8*>(&sX[tokA * 256 + ((kb * 32 + lg * 8) ^ swA)]);
  #pragma unroll
  for (int nt = 0; nt < 16; ++nt) {
    const u16* wp = woutT + (size_t)(nt * 16 + l15) * 256 + lg * 8;
    f32x4 acc = acc_out[nt];
    #pragma unroll
    for (int kb = 0; kb < 8; ++kb) {
      bf16x8 wA = *reinterpret_cast<const bf16x8*>(wp + kb * 32);
      acc = __builtin_amdgcn_mfma_f32_16x16x32_bf16(wA, oB[kb], acc, 0, 0, 0);
    }
    #pragma unroll
    for (int r = 0; r < 4; ++r) {
      int n = nt * 16 + lg * 4 + r;
      oimg[(size_t)n * HW + pixT] = acc[r];    // sectors merge in same-XCD L2
    }
  }
}

// ---------------- Kernel C: grouped conv1 + BN + ReLU (quarter tiles) ----------------
__global__ __launch_bounds__(256) void kc_conv1(
    const float* __restrict__ x2, const float* __restrict__ w1, const float* __restrict__ b1,
    const float* __restrict__ g1, const float* __restrict__ bb1,
    const float* __restrict__ m1, const float* __restrict__ v1,
    float* __restrict__ y1)
{
  __shared__ float sin_[4 * 22 * 72];
  int wid = blockIdx.x;
  int b = wid >> 8, rem = wid & 255, j = rem >> 2, qt = rem & 3;
  const float* img = x2 + (size_t)b * CCH * HW;
  for (int idx = threadIdx.x; idx < 4 * 22 * 70; idx += 256) {
    int i = idx / 1540, r2 = idx - i * 1540;
    int yy = r2 / 70, xx = r2 - yy * 70;
    int ih = qt * 16 + yy - 3, iw = xx - 3;
    float v = 0.f;
    if (ih >= 0 && ih < 64 && iw >= 0 && iw < 64)
      v = img[(size_t)(i * 64 + j) * HW + ih * 64 + iw];
    sin_[(i * 22 + yy) * 72 + xx] = v;
  }
  __syncthreads();

  float inv = g1[j] / sqrtf(v1[j] + 1e-5f);
  float shf = bb1[j] - m1[j] * inv;
  float bia = b1[j];
  float* yo = y1 + ((size_t)b * 64 + j) * HW + qt * 16 * 64;
  const float* wbase = w1 + j * 4 * 49;

  int y = threadIdx.x >> 4, x4 = (threadIdx.x & 15) * 4;
  float a0 = 0.f, a1 = 0.f, a2 = 0.f, a3 = 0.f;
  for (int i = 0; i < 4; ++i) {
    #pragma unroll
    for (int ky = 0; ky < 7; ++ky) {
      const float* row = sin_ + (i * 22 + y + ky) * 72 + x4;
      float v[10];
      #pragma unroll
      for (int q = 0; q < 10; ++q) v[q] = row[q];
      const float* wr = wbase + (i * 7 + ky) * 7;
      #pragma unroll
      for (int kx = 0; kx < 7; ++kx) {
        float wvv = wr[kx];
        a0 += v[kx] * wvv; a1 += v[kx+1] * wvv;
        a2 += v[kx+2] * wvv; a3 += v[kx+3] * wvv;
      }
    }
  }
  float4 r4;
  r4.x = fmaxf((a0 + bia) * inv + shf, 0.f);
  r4.y = fmaxf((a1 + bia) * inv + shf, 0.f);
  r4.z = fmaxf((a2 + bia) * inv + shf, 0.f);
  r4.w = fmaxf((a3 + bia) * inv + shf, 0.f);
  *reinterpret_cast<float4*>(yo + y * 64 + x4) = r4;
}

// ---------------- Kernel D: grouped conv2 + BN + sigmoid gate * shuffled x2 ----------------
__global__ __launch_bounds__(256) void kd_conv2(
    const float* __restrict__ y1, const float* __restrict__ x2,
    const float* __restrict__ w2, const float* __restrict__ b2,
    const float* __restrict__ g2, const float* __restrict__ bb2,
    const float* __restrict__ m2, const float* __restrict__ v2,
    float* __restrict__ out)
{
  __shared__ float sin_[70 * 72];
  int wid = blockIdx.x;
  int b = wid >> 6, g = wid & 63;
  const float* yin = y1 + ((size_t)b * 64 + g) * HW;
  for (int idx = threadIdx.x; idx < 70 * 70; idx += 256) {
    int yy = idx / 70, xx = idx - yy * 70;
    int ih = yy - 3, iw = xx - 3;
    float v = 0.f;
    if (ih >= 0 && ih < 64 && iw >= 0 && iw < 64) v = yin[ih * 64 + iw];
    sin_[yy * 72 + xx] = v;
  }
  __syncthreads();

  float inv[4], shf[4], bia[4];
  #pragma unroll
  for (int i = 0; i < 4; ++i) {
    int n = 4 * g + i;
    float sc = g2[n] / sqrtf(v2[n] + 1e-5f);
    inv[i] = sc; shf[i] = bb2[n] - m2[n] * sc; bia[i] = b2[n];
  }
  const float* wb = w2 + 4 * g * 49;

  for (int it = 0; it < 4; ++it) {
    int s = it * 256 + threadIdx.x;
    int y = s >> 4, x4 = (s & 15) * 4;
    float acc[4][4] = {};
    #pragma unroll
    for (int ky = 0; ky < 7; ++ky) {
      const float* row = sin_ + (y + ky) * 72 + x4;
      float v[10];
      #pragma unroll
      for (int q = 0; q < 10; ++q) v[q] = row[q];
      #pragma unroll
      for (int i = 0; i < 4; ++i) {
        const float* wr = wb + i * 49 + ky * 7;
        #pragma unroll
        for (int kx = 0; kx < 7; ++kx) {
          float wvv = wr[kx];
          acc[i][0] += v[kx] * wvv; acc[i][1] += v[kx+1] * wvv;
          acc[i][2] += v[kx+2] * wvv; acc[i][3] += v[kx+3] * wvv;
        }
      }
    }
    int po = y * 64 + x4;
    #pragma unroll
    for (int i = 0; i < 4; ++i) {
      int n = 4 * g + i;
      const float* xs = x2 + ((size_t)b * 256 + (i * 64 + g)) * HW + po;
      float* op = out + ((size_t)b * 256 + n) * HW + po;
      #pragma unroll
      for (int px = 0; px < 4; ++px) {
        float yv = (acc[i][px] + bia[i]) * inv[i] + shf[i];
        op[px] = xs[px] / (1.f + __expf(-yv));
      }
    }
  }
}

extern "C" void kernel_launch(void* const* d_in, const int* in_sizes, int n_in,
                              void* d_out, int out_size, void* d_ws, size_t ws_size,
                              hipStream_t stream) {
  const float* x     = (const float*)d_in[0];
  const float* qkv_w = (const float*)d_in[1];
  const float* qkv_b = (const float*)d_in[2];
  const float* out_w = (const float*)d_in[3];
  const float* out_b = (const float*)d_in[4];
  const float* ca_w1 = (const float*)d_in[5];
  const float* ca_b1 = (const float*)d_in[6];
  const float* ca_w2 = (const float*)d_in[7];
  const float* ca_b2 = (const float*)d_in[8];
  const float* sa_w1 = (const float*)d_in[9];
  const float* sa_b1 = (const float*)d_in[10];
  const float* bn1_g = (const float*)d_in[11];
  const float* bn1_b = (const float*)d_in[12];
  const float* bn1_m = (const float*)d_in[13];
  const float* bn1_v = (const float*)d_in[14];
  const float* sa_w2 = (const float*)d_in[15];
  const float* sa_b2 = (const float*)d_in[16];
  const float* bn2_g = (const float*)d_in[17];
  const float* bn2_b = (const float*)d_in[18];
  const float* bn2_m = (const float*)d_in[19];
  const float* bn2_v = (const float*)d_in[20];

  float* outp = (float*)d_out;
  float* x2 = (float*)d_ws;                         // xg + attn out
  float* y1 = x2 + (size_t)32 * 256 * 4096;         // conv1 output (b,64,64,64)

  // stash bf16 weight relayouts at the head of d_out (overwritten by kd at the end)
  u16* wqkvT = (u16*)d_out;                         // 196608
  u16* woutT = wqkvT + 768 * 256;                   // 65536
  u16* cw1t  = woutT + 256 * 256;                   // 16384
  u16* cw2t  = cw1t + 64 * 256;                     // 16384

  kprep   <<<768,  256, 0, stream>>>(qkv_w, out_w, ca_w1, ca_w2, wqkvT, woutT, cw1t, cw2t);
  kb_fused<<<2048, 256, 0, stream>>>(x, x2, wqkvT, qkv_b, woutT, out_b, cw1t, ca_b1, cw2t, ca_b2);
  kc_conv1<<<8192, 256, 0, stream>>>(x2, sa_w1, sa_b1, bn1_g, bn1_b, bn1_m, bn1_v, y1);
  kd_conv2<<<2048, 256, 0, stream>>>(y1, x2, sa_w2, sa_b2, bn2_g, bn2_b, bn2_m, bn2_v, outp);
}

// Round 6
// 796.110 us; speedup vs baseline: 2.1224x; 1.2249x over previous
//
#include <hip/hip_runtime.h>

#define HW 4096
#define CCH 256

typedef __bf16 bf16x8 __attribute__((ext_vector_type(8)));
typedef float f32x4 __attribute__((ext_vector_type(4)));
typedef unsigned short u16;

__device__ __forceinline__ u16 f2b(float f) {
  union { float f; unsigned u; } v; v.f = f;
  unsigned r = v.u + 0x7fff + ((v.u >> 16) & 1);   // RNE
  return (u16)(r >> 16);
}
__device__ __forceinline__ float b2f(u16 h) {
  union { unsigned u; float f; } v; v.u = ((unsigned)h) << 16; return v.f;
}

// ---------------- Kernel P: bf16 weight relayouts ----------------
__global__ __launch_bounds__(256) void kprep(
    const float* __restrict__ qkv_w, const float* __restrict__ out_w,
    const float* __restrict__ ca_w1, const float* __restrict__ ca_w2,
    u16* __restrict__ wqkvT, u16* __restrict__ woutT,
    u16* __restrict__ cw1t, u16* __restrict__ cw2t)
{
  int i = blockIdx.x * 256 + threadIdx.x;
  if (i < 768 * 256) wqkvT[i] = f2b(qkv_w[(i & 255) * 768 + (i >> 8)]);
  if (i < 256 * 256) woutT[i] = f2b(out_w[(i & 255) * 256 + (i >> 8)]);
  if (i < 64 * 256)  cw1t[i]  = f2b(ca_w1[(i & 255) * 64 + (i >> 8)]);
  if (i < 256 * 64)  cw2t[i]  = f2b(ca_w2[(i & 63) * 256 + (i >> 6)]);
}

// ---------------- Kernel B: fused CA-gate + windowed MHSA + out-proj ----------------
// one window per block; XCD-chunked swizzle; writes x2w[b][win][tok][c2] where
// c2 = (n&63)*4 + (n>>6)  (pre-applied channel shuffle)
__global__ __launch_bounds__(256, 2) void kb_fused(
    const float* __restrict__ x, float* __restrict__ x2w,
    const u16* __restrict__ wqkvT, const float* __restrict__ qkv_b,
    const u16* __restrict__ woutT, const float* __restrict__ out_b,
    const u16* __restrict__ cw1t, const float* __restrict__ ca_b1,
    const u16* __restrict__ cw2t, const float* __restrict__ ca_b2)
{
  __shared__ u16 sX[64 * 256];   // x -> xg -> O (per-head 64-col slices)   32 KB
  __shared__ u16 sQ[64 * 64];    // H -> Q -> P                              8 KB
  __shared__ u16 sK[64 * 64];    //                                          8 KB
  __shared__ u16 sVT[64 * 64];   // V^T [d][tok]                             8 KB

  const int tid = threadIdx.x;
  const int lane = tid & 63;
  const int wv = __builtin_amdgcn_readfirstlane(tid >> 6);
  const int l15 = lane & 15;
  const int lg = lane >> 4;

  const int bid = blockIdx.x;
  const int wid = (bid & 7) * 256 + (bid >> 3);   // XCD-chunked
  const int b = wid >> 6, wrem = wid & 63;
  const int pbase = (wrem >> 3) * (8 * 64) + (wrem & 7) * 8;
  const float* ximg = x + (size_t)b * CCH * HW;

  const int tokA = wv * 16 + l15;          // wave strip row
  const int swA = (tokA & 7) << 3;

  // ---- stage raw x -> sX via float4 (16 vector loads / thread) ----
  {
    const int t0 = l15 * 4;                                 // 4 tokens per lane
    const int prow = pbase + (l15 >> 1) * 64 + (l15 & 1) * 4;
    for (int i = 0; i < 16; ++i) {
      int c = i * 16 + wv * 4 + lg;
      const float4 v = *reinterpret_cast<const float4*>(&ximg[(size_t)c * HW + prow]);
      sX[(t0 + 0) * 256 + (c ^ (((t0 + 0) & 7) << 3))] = f2b(v.x);
      sX[(t0 + 1) * 256 + (c ^ (((t0 + 1) & 7) << 3))] = f2b(v.y);
      sX[(t0 + 2) * 256 + (c ^ (((t0 + 2) & 7) << 3))] = f2b(v.z);
      sX[(t0 + 3) * 256 + (c ^ (((t0 + 3) & 7) << 3))] = f2b(v.w);
    }
  }
  __syncthreads();

  // ---- channel-attention gating (per wave, strip-private; x from LDS) ----
  f32x4 acc_out[16];   // (row = out-channel, col = strip token); init xg + out_b
  {
    bf16x8 aXr[8];
    #pragma unroll
    for (int kb = 0; kb < 8; ++kb)
      aXr[kb] = *reinterpret_cast<const bf16x8*>(&sX[tokA * 256 + ((kb * 32 + lg * 8) ^ swA)]);
    #pragma unroll
    for (int nt1 = 0; nt1 < 4; ++nt1) {
      f32x4 c1 = {0.f, 0.f, 0.f, 0.f};
      #pragma unroll
      for (int kb = 0; kb < 8; ++kb) {
        bf16x8 bw = *reinterpret_cast<const bf16x8*>(&cw1t[(nt1 * 16 + l15) * 256 + kb * 32 + lg * 8]);
        c1 = __builtin_amdgcn_mfma_f32_16x16x32_bf16(aXr[kb], bw, c1, 0, 0, 0);
      }
      float bias1 = ca_b1[nt1 * 16 + l15];
      #pragma unroll
      for (int r = 0; r < 4; ++r) {
        int tok = wv * 16 + lg * 4 + r;
        sQ[tok * 64 + ((nt1 * 16 + l15) ^ ((tok & 7) << 3))] = f2b(fmaxf(c1[r] + bias1, 0.f));
      }
    }
    bf16x8 hB[2];
    #pragma unroll
    for (int kb = 0; kb < 2; ++kb)
      hB[kb] = *reinterpret_cast<const bf16x8*>(&sQ[tokA * 64 + ((kb * 32 + lg * 8) ^ swA)]);
    #pragma unroll
    for (int nt = 0; nt < 16; ++nt) {
      f32x4 a2 = {0.f, 0.f, 0.f, 0.f};
      #pragma unroll
      for (int kb = 0; kb < 2; ++kb) {
        bf16x8 w2a = *reinterpret_cast<const bf16x8*>(&cw2t[(nt * 16 + l15) * 64 + kb * 32 + lg * 8]);
        a2 = __builtin_amdgcn_mfma_f32_16x16x32_bf16(w2a, hB[kb], a2, 0, 0, 0);
      }
      const int n0 = nt * 16 + lg * 4;
      const ushort4 xq = *reinterpret_cast<const ushort4*>(&sX[tokA * 256 + (n0 ^ swA)]);
      u16 xg16[4];
      #pragma unroll
      for (int r = 0; r < 4; ++r) {
        int n = n0 + r;
        float av = a2[r] + ca_b2[n];
        float xv = b2f(r == 0 ? xq.x : r == 1 ? xq.y : r == 2 ? xq.z : xq.w);
        float xgf = xv / (1.f + __expf(-av));
        acc_out[nt][r] = xgf + out_b[n];
        xg16[r] = f2b(xgf);
      }
      uint2 pk;
      pk.x = xg16[0] | ((unsigned)xg16[1] << 16);
      pk.y = xg16[2] | ((unsigned)xg16[3] << 16);
      *reinterpret_cast<uint2*>(&sX[tokA * 256 + (n0 ^ swA)]) = pk;  // xg overwrites x
    }
  }
  __syncthreads();

  // ---- hoist all QKV A-fragments (xg window) into registers ----
  bf16x8 A_all[32];
  #pragma unroll
  for (int t = 0; t < 4; ++t) {
    int arow = t * 16 + l15;
    int asw = (arow & 7) << 3;
    #pragma unroll
    for (int kb = 0; kb < 8; ++kb)
      A_all[t * 8 + kb] = *reinterpret_cast<const bf16x8*>(&sX[arow * 256 + ((kb * 32 + lg * 8) ^ asw)]);
  }

  for (int h = 0; h < 4; ++h) {
    // ---------- QKV: wave owns 3 col-tiles; B loaded once, A from regs ----------
    #pragma unroll
    for (int ti = 0; ti < 3; ++ti) {
      int tau = wv * 3 + ti;
      int kind = tau >> 2, sub = tau & 3;
      int colbase = kind * 256 + h * 64 + sub * 16;
      const u16* wp = wqkvT + (size_t)(colbase + l15) * 256 + lg * 8;
      bf16x8 Bf[8];
      #pragma unroll
      for (int kb = 0; kb < 8; ++kb)
        Bf[kb] = *reinterpret_cast<const bf16x8*>(wp + kb * 32);
      float bias = qkv_b[colbase + l15];
      #pragma unroll
      for (int t = 0; t < 4; ++t) {
        f32x4 acc = {0.f, 0.f, 0.f, 0.f};
        #pragma unroll
        for (int kb = 0; kb < 8; ++kb)
          acc = __builtin_amdgcn_mfma_f32_16x16x32_bf16(A_all[t * 8 + kb], Bf[kb], acc, 0, 0, 0);
        #pragma unroll
        for (int r = 0; r < 4; ++r) {
          int tok = t * 16 + lg * 4 + r;
          u16 uv = f2b(acc[r] + bias);
          int d = sub * 16 + l15;
          int sw = (tok & 7) << 3;
          if (kind == 0)      sQ [tok * 64 + (d ^ sw)] = uv;
          else if (kind == 1) sK [tok * 64 + (d ^ sw)] = uv;
          else                sVT[d * 64 + (tok ^ ((d & 7) << 3))] = uv;
        }
      }
    }
    __syncthreads();

    // ---------- scores S = Q @ K^T (strip rows) ----------
    bf16x8 aQ[2];
    #pragma unroll
    for (int kb = 0; kb < 2; ++kb)
      aQ[kb] = *reinterpret_cast<const bf16x8*>(&sQ[tokA * 64 + ((kb * 32 + lg * 8) ^ swA)]);
    f32x4 s4[4];
    #pragma unroll
    for (int jt = 0; jt < 4; ++jt) {
      int krow = jt * 16 + l15;
      int swk = (krow & 7) << 3;
      f32x4 acc = {0.f, 0.f, 0.f, 0.f};
      #pragma unroll
      for (int kb = 0; kb < 2; ++kb) {
        bf16x8 bK = *reinterpret_cast<const bf16x8*>(&sK[krow * 64 + ((kb * 32 + lg * 8) ^ swk)]);
        acc = __builtin_amdgcn_mfma_f32_16x16x32_bf16(aQ[kb], bK, acc, 0, 0, 0);
      }
      s4[jt] = acc;
    }
    // ---------- softmax per row, P overwrites own sQ strip ----------
    #pragma unroll
    for (int r = 0; r < 4; ++r) {
      float m = fmaxf(fmaxf(s4[0][r], s4[1][r]), fmaxf(s4[2][r], s4[3][r]));
      #pragma unroll
      for (int off = 1; off < 16; off <<= 1) m = fmaxf(m, __shfl_xor(m, off));
      float e0 = __expf((s4[0][r] - m) * 0.125f);
      float e1 = __expf((s4[1][r] - m) * 0.125f);
      float e2 = __expf((s4[2][r] - m) * 0.125f);
      float e3 = __expf((s4[3][r] - m) * 0.125f);
      float sum = e0 + e1 + e2 + e3;
      #pragma unroll
      for (int off = 1; off < 16; off <<= 1) sum += __shfl_xor(sum, off);
      float is = 1.f / sum;
      int tok = wv * 16 + lg * 4 + r;
      int swp = (tok & 7) << 3;
      sQ[tok * 64 + ((     l15) ^ swp)] = f2b(e0 * is);
      sQ[tok * 64 + ((16 + l15) ^ swp)] = f2b(e1 * is);
      sQ[tok * 64 + ((32 + l15) ^ swp)] = f2b(e2 * is);
      sQ[tok * 64 + ((48 + l15) ^ swp)] = f2b(e3 * is);
    }
    // ---------- PV: O^T = V^T @ P^T (strip-private) ----------
    bf16x8 bP[2];
    #pragma unroll
    for (int kb = 0; kb < 2; ++kb)
      bP[kb] = *reinterpret_cast<const bf16x8*>(&sQ[tokA * 64 + ((kb * 32 + lg * 8) ^ swA)]);
    f32x4 o4[4];
    #pragma unroll
    for (int dt = 0; dt < 4; ++dt) {
      int drow = dt * 16 + l15;
      int swd = (drow & 7) << 3;
      f32x4 acc = {0.f, 0.f, 0.f, 0.f};
      #pragma unroll
      for (int kb = 0; kb < 2; ++kb) {
        bf16x8 aV = *reinterpret_cast<const bf16x8*>(&sVT[drow * 64 + ((kb * 32 + lg * 8) ^ swd)]);
        acc = __builtin_amdgcn_mfma_f32_16x16x32_bf16(aV, bP[kb], acc, 0, 0, 0);
      }
      o4[dt] = acc;
    }
    // O_h -> sX[tok][h*64 + d]  (own strip rows)
    #pragma unroll
    for (int dt = 0; dt < 4; ++dt) {
      int d0 = h * 64 + dt * 16 + lg * 4;
      uint2 pk;
      pk.x = f2b(o4[dt][0]) | ((unsigned)f2b(o4[dt][1]) << 16);
      pk.y = f2b(o4[dt][2]) | ((unsigned)f2b(o4[dt][3]) << 16);
      *reinterpret_cast<uint2*>(&sX[tokA * 256 + (d0 ^ swA)]) = pk;
    }
    __syncthreads();
  }

  // ---------- out-proj (K=256, swapped operands), accumulate in place ----------
  bf16x8 oB[8];
  #pragma unroll
  for (int kb = 0; kb < 8; ++kb)
    oB[kb] = *reinterpret_cast<const bf16x8*>(&sX[tokA * 256 + ((kb * 32 + lg * 8) ^ swA)]);
  #pragma unroll
  for (int nt = 0; nt < 16; ++nt) {
    const u16* wp = woutT + (size_t)(nt * 16 + l15) * 256 + lg * 8;
    #pragma unroll
    for (int kb = 0; kb < 8; ++kb) {
      bf16x8 wA = *reinterpret_cast<const bf16x8*>(wp + kb * 32);
      acc_out[nt] = __builtin_amdgcn_mfma_f32_16x16x32_bf16(wA, oB[kb], acc_out[nt], 0, 0, 0);
    }
  }

  // ---------- store x2w[b][wrem][tokA][c2] as float4 (full-line, block-exclusive) ----------
  {
    float* wout = x2w + ((size_t)(b * 64 + wrem) * 64 + tokA) * 256;
    #pragma unroll
    for (int nt0 = 0; nt0 < 4; ++nt0) {
      #pragma unroll
      for (int r = 0; r < 4; ++r) {
        int c2 = (nt0 * 16 + lg * 4 + r) * 4;     // quad {c, c+64, c+128, c+192}
        float4 f;
        f.x = acc_out[nt0     ][r];
        f.y = acc_out[nt0 +  4][r];
        f.z = acc_out[nt0 +  8][r];
        f.w = acc_out[nt0 + 12][r];
        *reinterpret_cast<float4*>(&wout[c2]) = f;
      }
    }
  }
}

// ---------------- Kernel C: grouped conv1 + BN + ReLU (quarter tiles, x2w input) ----------------
__global__ __launch_bounds__(256) void kc_conv1(
    const float* __restrict__ x2w, const float* __restrict__ w1, const float* __restrict__ b1,
    const float* __restrict__ g1, const float* __restrict__ bb1,
    const float* __restrict__ m1, const float* __restrict__ v1,
    float* __restrict__ y1)
{
  __shared__ float sin_[4 * 22 * 72];
  const int bid = blockIdx.x;
  const int wid = (bid & 7) * 1024 + (bid >> 3);     // XCD-chunked (4 batches/XCD)
  int b = wid >> 8, rem = wid & 255, j = rem >> 2, qt = rem & 3;
  const float* xw = x2w + (size_t)b * 64 * 64 * 256;
  for (int idx = threadIdx.x; idx < 22 * 70; idx += 256) {
    int yy = idx / 70, xx = idx - yy * 70;
    int ih = qt * 16 + yy - 3, iw = xx - 3;
    float4 v = {0.f, 0.f, 0.f, 0.f};
    if (ih >= 0 && ih < 64 && iw >= 0 && iw < 64) {
      int wr = (ih >> 3) * 8 + (iw >> 3);
      int tok = (ih & 7) * 8 + (iw & 7);
      v = *reinterpret_cast<const float4*>(&xw[((size_t)wr * 64 + tok) * 256 + 4 * j]);
    }
    sin_[0 * 1584 + yy * 72 + xx] = v.x;
    sin_[1 * 1584 + yy * 72 + xx] = v.y;
    sin_[2 * 1584 + yy * 72 + xx] = v.z;
    sin_[3 * 1584 + yy * 72 + xx] = v.w;
  }
  __syncthreads();

  float inv = g1[j] / sqrtf(v1[j] + 1e-5f);
  float shf = bb1[j] - m1[j] * inv;
  float bia = b1[j];
  float* yo = y1 + ((size_t)b * 64 + j) * HW + qt * 16 * 64;
  const float* wbase = w1 + j * 4 * 49;

  int y = threadIdx.x >> 4, x4 = (threadIdx.x & 15) * 4;
  float a0 = 0.f, a1 = 0.f, a2 = 0.f, a3 = 0.f;
  for (int i = 0; i < 4; ++i) {
    #pragma unroll
    for (int ky = 0; ky < 7; ++ky) {
      const float* row = sin_ + (i * 22 + y + ky) * 72 + x4;
      float v[10];
      #pragma unroll
      for (int q = 0; q < 10; ++q) v[q] = row[q];
      const float* wr = wbase + (i * 7 + ky) * 7;
      #pragma unroll
      for (int kx = 0; kx < 7; ++kx) {
        float wvv = wr[kx];
        a0 += v[kx] * wvv; a1 += v[kx+1] * wvv;
        a2 += v[kx+2] * wvv; a3 += v[kx+3] * wvv;
      }
    }
  }
  float4 r4;
  r4.x = fmaxf((a0 + bia) * inv + shf, 0.f);
  r4.y = fmaxf((a1 + bia) * inv + shf, 0.f);
  r4.z = fmaxf((a2 + bia) * inv + shf, 0.f);
  r4.w = fmaxf((a3 + bia) * inv + shf, 0.f);
  *reinterpret_cast<float4*>(yo + y * 64 + x4) = r4;
}

// ---------------- Kernel D: grouped conv2 + BN + sigmoid gate * x2w ----------------
__global__ __launch_bounds__(256) void kd_conv2(
    const float* __restrict__ y1, const float* __restrict__ x2w,
    const float* __restrict__ w2, const float* __restrict__ b2,
    const float* __restrict__ g2, const float* __restrict__ bb2,
    const float* __restrict__ m2, const float* __restrict__ v2,
    float* __restrict__ out)
{
  __shared__ float sin_[70 * 72];
  const int bid = blockIdx.x;
  const int wid = (bid & 7) * 256 + (bid >> 3);      // XCD-chunked (4 batches/XCD)
  int b = wid >> 6, g = wid & 63;
  const float* yin = y1 + ((size_t)b * 64 + g) * HW;
  for (int idx = threadIdx.x; idx < 70 * 70; idx += 256) {
    int yy = idx / 70, xx = idx - yy * 70;
    int ih = yy - 3, iw = xx - 3;
    float v = 0.f;
    if (ih >= 0 && ih < 64 && iw >= 0 && iw < 64) v = yin[ih * 64 + iw];
    sin_[yy * 72 + xx] = v;
  }
  __syncthreads();

  float inv[4], shf[4], bia[4];
  #pragma unroll
  for (int i = 0; i < 4; ++i) {
    int n = 4 * g + i;
    float sc = g2[n] / sqrtf(v2[n] + 1e-5f);
    inv[i] = sc; shf[i] = bb2[n] - m2[n] * sc; bia[i] = b2[n];
  }
  const float* wb = w2 + 4 * g * 49;
  const float* xw = x2w + (size_t)b * 64 * 64 * 256;

  for (int it = 0; it < 4; ++it) {
    int s = it * 256 + threadIdx.x;
    int y = s >> 4, x4 = (s & 15) * 4;
    float acc[4][4] = {};
    #pragma unroll
    for (int ky = 0; ky < 7; ++ky) {
      const float* row = sin_ + (y + ky) * 72 + x4;
      float v[10];
      #pragma unroll
      for (int q = 0; q < 10; ++q) v[q] = row[q];
      #pragma unroll
      for (int i = 0; i < 4; ++i) {
        const float* wr = wb + i * 49 + ky * 7;
        #pragma unroll
        for (int kx = 0; kx < 7; ++kx) {
          float wvv = wr[kx];
          acc[i][0] += v[kx] * wvv; acc[i][1] += v[kx+1] * wvv;
          acc[i][2] += v[kx+2] * wvv; acc[i][3] += v[kx+3] * wvv;
        }
      }
    }
    int po = y * 64 + x4;
    // gate reads: 4 pixels, channels 4g..4g+3 each (pre-shuffled = x_sh)
    int wr_ = (y >> 3) * 8 + (x4 >> 3);
    int t0 = (y & 7) * 8 + (x4 & 7);
    const float* gp = &xw[((size_t)wr_ * 64 + t0) * 256 + 4 * g];
    float4 gx0 = *reinterpret_cast<const float4*>(gp + 0 * 256);
    float4 gx1 = *reinterpret_cast<const float4*>(gp + 1 * 256);
    float4 gx2 = *reinterpret_cast<const float4*>(gp + 2 * 256);
    float4 gx3 = *reinterpret_cast<const float4*>(gp + 3 * 256);
    #pragma unroll
    for (int i = 0; i < 4; ++i) {
      int n = 4 * g + i;
      float* op = out + ((size_t)b * 256 + n) * HW + po;
      float y0 = (acc[i][0] + bia[i]) * inv[i] + shf[i];
      float y1v = (acc[i][1] + bia[i]) * inv[i] + shf[i];
      float y2 = (acc[i][2] + bia[i]) * inv[i] + shf[i];
      float y3 = (acc[i][3] + bia[i]) * inv[i] + shf[i];
      float4 r;
      const float* g0 = reinterpret_cast<const float*>(&gx0);
      const float* g1 = reinterpret_cast<const float*>(&gx1);
      const float* g2p = reinterpret_cast<const float*>(&gx2);
      const float* g3 = reinterpret_cast<const float*>(&gx3);
      r.x = g0[i] / (1.f + __expf(-y0));
      r.y = g1[i] / (1.f + __expf(-y1v));
      r.z = g2p[i] / (1.f + __expf(-y2));
      r.w = g3[i] / (1.f + __expf(-y3));
      *reinterpret_cast<float4*>(op) = r;
    }
  }
}

extern "C" void kernel_launch(void* const* d_in, const int* in_sizes, int n_in,
                              void* d_out, int out_size, void* d_ws, size_t ws_size,
                              hipStream_t stream) {
  const float* x     = (const float*)d_in[0];
  const float* qkv_w = (const float*)d_in[1];
  const float* qkv_b = (const float*)d_in[2];
  const float* out_w = (const float*)d_in[3];
  const float* out_b = (const float*)d_in[4];
  const float* ca_w1 = (const float*)d_in[5];
  const float* ca_b1 = (const float*)d_in[6];
  const float* ca_w2 = (const float*)d_in[7];
  const float* ca_b2 = (const float*)d_in[8];
  const float* sa_w1 = (const float*)d_in[9];
  const float* sa_b1 = (const float*)d_in[10];
  const float* bn1_g = (const float*)d_in[11];
  const float* bn1_b = (const float*)d_in[12];
  const float* bn1_m = (const float*)d_in[13];
  const float* bn1_v = (const float*)d_in[14];
  const float* sa_w2 = (const float*)d_in[15];
  const float* sa_b2 = (const float*)d_in[16];
  const float* bn2_g = (const float*)d_in[17];
  const float* bn2_b = (const float*)d_in[18];
  const float* bn2_m = (const float*)d_in[19];
  const float* bn2_v = (const float*)d_in[20];

  float* outp = (float*)d_out;
  float* x2w = (float*)d_ws;                        // [b][win][tok][c2] fp32, 128 MB
  float* y1 = x2w + (size_t)32 * 64 * 64 * 256;     // conv1 output (b,64,64,64)

  // stash bf16 weight relayouts at the head of d_out (overwritten by kd at the end)
  u16* wqkvT = (u16*)d_out;                         // 196608
  u16* woutT = wqkvT + 768 * 256;                   // 65536
  u16* cw1t  = woutT + 256 * 256;                   // 16384
  u16* cw2t  = cw1t + 64 * 256;                     // 16384

  kprep   <<<768,  256, 0, stream>>>(qkv_w, out_w, ca_w1, ca_w2, wqkvT, woutT, cw1t, cw2t);
  kb_fused<<<2048, 256, 0, stream>>>(x, x2w, wqkvT, qkv_b, woutT, out_b, cw1t, ca_b1, cw2t, ca_b2);
  kc_conv1<<<8192, 256, 0, stream>>>(x2w, sa_w1, sa_b1, bn1_g, bn1_b, bn1_m, bn1_v, y1);
  kd_conv2<<<2048, 256, 0, stream>>>(y1, x2w, sa_w2, sa_b2, bn2_g, bn2_b, bn2_m, bn2_v, outp);
}

// Round 7
// 771.976 us; speedup vs baseline: 2.1888x; 1.0313x over previous
//
#include <hip/hip_runtime.h>

#define HW 4096
#define CCH 256

typedef __bf16 bf16x8 __attribute__((ext_vector_type(8)));
typedef float f32x4 __attribute__((ext_vector_type(4)));
typedef unsigned short u16;

// LDS row swizzle: spreads 8 ways even when rows step by 4 (staging/QKV writes)
#define SWZ8(r) ((((r) + ((r) >> 2)) & 7) << 3)

__device__ __forceinline__ u16 f2b(float f) {
  union { float f; unsigned u; } v; v.f = f;
  unsigned r = v.u + 0x7fff + ((v.u >> 16) & 1);   // RNE
  return (u16)(r >> 16);
}
__device__ __forceinline__ float b2f(u16 h) {
  union { unsigned u; float f; } v; v.u = ((unsigned)h) << 16; return v.f;
}

// ---------------- Kernel P: bf16 weight relayouts ----------------
__global__ __launch_bounds__(256) void kprep(
    const float* __restrict__ qkv_w, const float* __restrict__ out_w,
    const float* __restrict__ ca_w1, const float* __restrict__ ca_w2,
    u16* __restrict__ wqkvT, u16* __restrict__ woutT,
    u16* __restrict__ cw1t, u16* __restrict__ cw2t)
{
  int i = blockIdx.x * 256 + threadIdx.x;
  if (i < 768 * 256) wqkvT[i] = f2b(qkv_w[(i & 255) * 768 + (i >> 8)]);
  if (i < 256 * 256) woutT[i] = f2b(out_w[(i & 255) * 256 + (i >> 8)]);
  if (i < 64 * 256)  cw1t[i]  = f2b(ca_w1[(i & 255) * 64 + (i >> 8)]);
  if (i < 256 * 64)  cw2t[i]  = f2b(ca_w2[(i & 63) * 256 + (i >> 6)]);
}

// ---------------- Kernel B: fused CA-gate + windowed MHSA + out-proj ----------------
// one window per block; XCD-chunked swizzle; writes x2w[win][cq][tok][quad]
// where channel n = quad*64 + cq (pre-applied channel shuffle). Each store
// instruction covers full 128-B lines (lane = token, contiguous).
__global__ __launch_bounds__(256, 2) void kb_fused(
    const float* __restrict__ x, float* __restrict__ x2w,
    const u16* __restrict__ wqkvT, const float* __restrict__ qkv_b,
    const u16* __restrict__ woutT, const float* __restrict__ out_b,
    const u16* __restrict__ cw1t, const float* __restrict__ ca_b1,
    const u16* __restrict__ cw2t, const float* __restrict__ ca_b2)
{
  __shared__ u16 sX[64 * 256];   // x -> xg -> O (per-head 64-col slices)   32 KB
  __shared__ u16 sQ[64 * 64];    // H -> Q -> P                              8 KB
  __shared__ u16 sK[64 * 64];    //                                          8 KB
  __shared__ u16 sVT[64 * 64];   // V^T [d][tok]                             8 KB

  const int tid = threadIdx.x;
  const int lane = tid & 63;
  const int wv = __builtin_amdgcn_readfirstlane(tid >> 6);
  const int l15 = lane & 15;
  const int lg = lane >> 4;

  const int bid = blockIdx.x;
  const int wid = (bid & 7) * 256 + (bid >> 3);   // XCD-chunked
  const int b = wid >> 6, wrem = wid & 63;
  const int pbase = (wrem >> 3) * (8 * 64) + (wrem & 7) * 8;
  const float* ximg = x + (size_t)b * CCH * HW;

  const int tokA = wv * 16 + l15;          // wave strip row
  const int swA = SWZ8(tokA);

  // ---- stage raw x -> sX via float4 (16 vector loads / thread) ----
  {
    const int t0 = l15 * 4;                                 // 4 tokens per lane
    const int prow = pbase + (l15 >> 1) * 64 + (l15 & 1) * 4;
    for (int i = 0; i < 16; ++i) {
      int c = i * 16 + wv * 4 + lg;
      const float4 v = *reinterpret_cast<const float4*>(&ximg[(size_t)c * HW + prow]);
      sX[(t0 + 0) * 256 + (c ^ SWZ8(t0 + 0))] = f2b(v.x);
      sX[(t0 + 1) * 256 + (c ^ SWZ8(t0 + 1))] = f2b(v.y);
      sX[(t0 + 2) * 256 + (c ^ SWZ8(t0 + 2))] = f2b(v.z);
      sX[(t0 + 3) * 256 + (c ^ SWZ8(t0 + 3))] = f2b(v.w);
    }
  }
  __syncthreads();

  // ---- channel-attention gating (per wave, strip-private; x from LDS) ----
  f32x4 acc_out[16];   // (row = out-channel, col = strip token); init xg + out_b
  {
    bf16x8 aXr[8];
    #pragma unroll
    for (int kb = 0; kb < 8; ++kb)
      aXr[kb] = *reinterpret_cast<const bf16x8*>(&sX[tokA * 256 + ((kb * 32 + lg * 8) ^ swA)]);
    #pragma unroll
    for (int nt1 = 0; nt1 < 4; ++nt1) {
      f32x4 c1 = {0.f, 0.f, 0.f, 0.f};
      #pragma unroll
      for (int kb = 0; kb < 8; ++kb) {
        bf16x8 bw = *reinterpret_cast<const bf16x8*>(&cw1t[(nt1 * 16 + l15) * 256 + kb * 32 + lg * 8]);
        c1 = __builtin_amdgcn_mfma_f32_16x16x32_bf16(aXr[kb], bw, c1, 0, 0, 0);
      }
      float bias1 = ca_b1[nt1 * 16 + l15];
      #pragma unroll
      for (int r = 0; r < 4; ++r) {
        int tok = wv * 16 + lg * 4 + r;
        sQ[tok * 64 + ((nt1 * 16 + l15) ^ SWZ8(tok))] = f2b(fmaxf(c1[r] + bias1, 0.f));
      }
    }
    bf16x8 hB[2];
    #pragma unroll
    for (int kb = 0; kb < 2; ++kb)
      hB[kb] = *reinterpret_cast<const bf16x8*>(&sQ[tokA * 64 + ((kb * 32 + lg * 8) ^ swA)]);
    #pragma unroll
    for (int nt = 0; nt < 16; ++nt) {
      f32x4 a2 = {0.f, 0.f, 0.f, 0.f};
      #pragma unroll
      for (int kb = 0; kb < 2; ++kb) {
        bf16x8 w2a = *reinterpret_cast<const bf16x8*>(&cw2t[(nt * 16 + l15) * 64 + kb * 32 + lg * 8]);
        a2 = __builtin_amdgcn_mfma_f32_16x16x32_bf16(w2a, hB[kb], a2, 0, 0, 0);
      }
      const int n0 = nt * 16 + lg * 4;
      const ushort4 xq = *reinterpret_cast<const ushort4*>(&sX[tokA * 256 + (n0 ^ swA)]);
      u16 xg16[4];
      #pragma unroll
      for (int r = 0; r < 4; ++r) {
        int n = n0 + r;
        float av = a2[r] + ca_b2[n];
        float xv = b2f(r == 0 ? xq.x : r == 1 ? xq.y : r == 2 ? xq.z : xq.w);
        float xgf = xv / (1.f + __expf(-av));
        acc_out[nt][r] = xgf + out_b[n];
        xg16[r] = f2b(xgf);
      }
      uint2 pk;
      pk.x = xg16[0] | ((unsigned)xg16[1] << 16);
      pk.y = xg16[2] | ((unsigned)xg16[3] << 16);
      *reinterpret_cast<uint2*>(&sX[tokA * 256 + (n0 ^ swA)]) = pk;  // xg overwrites x
    }
  }
  __syncthreads();

  // ---- hoist all QKV A-fragments (xg window) into registers ----
  bf16x8 A_all[32];
  #pragma unroll
  for (int t = 0; t < 4; ++t) {
    int arow = t * 16 + l15;
    int asw = SWZ8(arow);
    #pragma unroll
    for (int kb = 0; kb < 8; ++kb)
      A_all[t * 8 + kb] = *reinterpret_cast<const bf16x8*>(&sX[arow * 256 + ((kb * 32 + lg * 8) ^ asw)]);
  }

  for (int h = 0; h < 4; ++h) {
    // ---------- QKV: wave owns 3 col-tiles; B loaded once, A from regs ----------
    #pragma unroll
    for (int ti = 0; ti < 3; ++ti) {
      int tau = wv * 3 + ti;
      int kind = tau >> 2, sub = tau & 3;
      int colbase = kind * 256 + h * 64 + sub * 16;
      const u16* wp = wqkvT + (size_t)(colbase + l15) * 256 + lg * 8;
      bf16x8 Bf[8];
      #pragma unroll
      for (int kb = 0; kb < 8; ++kb)
        Bf[kb] = *reinterpret_cast<const bf16x8*>(wp + kb * 32);
      float bias = qkv_b[colbase + l15];
      #pragma unroll
      for (int t = 0; t < 4; ++t) {
        f32x4 acc = {0.f, 0.f, 0.f, 0.f};
        #pragma unroll
        for (int kb = 0; kb < 8; ++kb)
          acc = __builtin_amdgcn_mfma_f32_16x16x32_bf16(A_all[t * 8 + kb], Bf[kb], acc, 0, 0, 0);
        #pragma unroll
        for (int r = 0; r < 4; ++r) {
          int tok = t * 16 + lg * 4 + r;
          u16 uv = f2b(acc[r] + bias);
          int d = sub * 16 + l15;
          if (kind == 0)      sQ [tok * 64 + (d ^ SWZ8(tok))] = uv;
          else if (kind == 1) sK [tok * 64 + (d ^ SWZ8(tok))] = uv;
          else                sVT[d * 64 + (tok ^ ((d & 7) << 3))] = uv;
        }
      }
    }
    __syncthreads();

    // ---------- scores S = Q @ K^T (strip rows) ----------
    bf16x8 aQ[2];
    #pragma unroll
    for (int kb = 0; kb < 2; ++kb)
      aQ[kb] = *reinterpret_cast<const bf16x8*>(&sQ[tokA * 64 + ((kb * 32 + lg * 8) ^ swA)]);
    f32x4 s4[4];
    #pragma unroll
    for (int jt = 0; jt < 4; ++jt) {
      int krow = jt * 16 + l15;
      int swk = SWZ8(krow);
      f32x4 acc = {0.f, 0.f, 0.f, 0.f};
      #pragma unroll
      for (int kb = 0; kb < 2; ++kb) {
        bf16x8 bK = *reinterpret_cast<const bf16x8*>(&sK[krow * 64 + ((kb * 32 + lg * 8) ^ swk)]);
        acc = __builtin_amdgcn_mfma_f32_16x16x32_bf16(aQ[kb], bK, acc, 0, 0, 0);
      }
      s4[jt] = acc;
    }
    // ---------- softmax per row, P overwrites own sQ strip ----------
    #pragma unroll
    for (int r = 0; r < 4; ++r) {
      float m = fmaxf(fmaxf(s4[0][r], s4[1][r]), fmaxf(s4[2][r], s4[3][r]));
      #pragma unroll
      for (int off = 1; off < 16; off <<= 1) m = fmaxf(m, __shfl_xor(m, off));
      float e0 = __expf((s4[0][r] - m) * 0.125f);
      float e1 = __expf((s4[1][r] - m) * 0.125f);
      float e2 = __expf((s4[2][r] - m) * 0.125f);
      float e3 = __expf((s4[3][r] - m) * 0.125f);
      float sum = e0 + e1 + e2 + e3;
      #pragma unroll
      for (int off = 1; off < 16; off <<= 1) sum += __shfl_xor(sum, off);
      float is = 1.f / sum;
      int tok = wv * 16 + lg * 4 + r;
      int swp = SWZ8(tok);
      sQ[tok * 64 + ((     l15) ^ swp)] = f2b(e0 * is);
      sQ[tok * 64 + ((16 + l15) ^ swp)] = f2b(e1 * is);
      sQ[tok * 64 + ((32 + l15) ^ swp)] = f2b(e2 * is);
      sQ[tok * 64 + ((48 + l15) ^ swp)] = f2b(e3 * is);
    }
    // ---------- PV: O^T = V^T @ P^T (strip-private) ----------
    bf16x8 bP[2];
    #pragma unroll
    for (int kb = 0; kb < 2; ++kb)
      bP[kb] = *reinterpret_cast<const bf16x8*>(&sQ[tokA * 64 + ((kb * 32 + lg * 8) ^ swA)]);
    f32x4 o4[4];
    #pragma unroll
    for (int dt = 0; dt < 4; ++dt) {
      int drow = dt * 16 + l15;
      int swd = (drow & 7) << 3;
      f32x4 acc = {0.f, 0.f, 0.f, 0.f};
      #pragma unroll
      for (int kb = 0; kb < 2; ++kb) {
        bf16x8 aV = *reinterpret_cast<const bf16x8*>(&sVT[drow * 64 + ((kb * 32 + lg * 8) ^ swd)]);
        acc = __builtin_amdgcn_mfma_f32_16x16x32_bf16(aV, bP[kb], acc, 0, 0, 0);
      }
      o4[dt] = acc;
    }
    // O_h -> sX[tok][h*64 + d]  (own strip rows)
    #pragma unroll
    for (int dt = 0; dt < 4; ++dt) {
      int d0 = h * 64 + dt * 16 + lg * 4;
      uint2 pk;
      pk.x = f2b(o4[dt][0]) | ((unsigned)f2b(o4[dt][1]) << 16);
      pk.y = f2b(o4[dt][2]) | ((unsigned)f2b(o4[dt][3]) << 16);
      *reinterpret_cast<uint2*>(&sX[tokA * 256 + (d0 ^ swA)]) = pk;
    }
    __syncthreads();
  }

  // ---------- out-proj (K=256, swapped operands), accumulate in place ----------
  bf16x8 oB[8];
  #pragma unroll
  for (int kb = 0; kb < 8; ++kb)
    oB[kb] = *reinterpret_cast<const bf16x8*>(&sX[tokA * 256 + ((kb * 32 + lg * 8) ^ swA)]);
  #pragma unroll
  for (int nt = 0; nt < 16; ++nt) {
    const u16* wp = woutT + (size_t)(nt * 16 + l15) * 256 + lg * 8;
    #pragma unroll
    for (int kb = 0; kb < 8; ++kb) {
      bf16x8 wA = *reinterpret_cast<const bf16x8*>(wp + kb * 32);
      acc_out[nt] = __builtin_amdgcn_mfma_f32_16x16x32_bf16(wA, oB[kb], acc_out[nt], 0, 0, 0);
    }
  }

  // ---------- store x2w[wid][cq][tokA][quad]: 8 full 128-B lines / instr ----------
  {
    float* wout = x2w + (size_t)wid * 16384;
    #pragma unroll
    for (int nt0 = 0; nt0 < 4; ++nt0) {
      #pragma unroll
      for (int r = 0; r < 4; ++r) {
        int cq = nt0 * 16 + lg * 4 + r;           // channel-quad id 0..63
        float4 f;
        f.x = acc_out[nt0     ][r];               // quad = {cq, 64+cq, 128+cq, 192+cq}
        f.y = acc_out[nt0 +  4][r];
        f.z = acc_out[nt0 +  8][r];
        f.w = acc_out[nt0 + 12][r];
        *reinterpret_cast<float4*>(&wout[cq * 256 + tokA * 4]) = f;
      }
    }
  }
}

// ---------------- Kernel C: grouped conv1 + BN + ReLU (quarter tiles, x2w input) ----------------
__global__ __launch_bounds__(256) void kc_conv1(
    const float* __restrict__ x2w, const float* __restrict__ w1, const float* __restrict__ b1,
    const float* __restrict__ g1, const float* __restrict__ bb1,
    const float* __restrict__ m1, const float* __restrict__ v1,
    float* __restrict__ y1)
{
  __shared__ float sin_[4 * 22 * 72];
  const int bid = blockIdx.x;
  const int wid = (bid & 7) * 1024 + (bid >> 3);     // XCD-chunked (4 batches/XCD)
  int b = wid >> 8, rem = wid & 255, j = rem >> 2, qt = rem & 3;
  const float* xw = x2w + (size_t)b * 64 * 16384;
  for (int idx = threadIdx.x; idx < 22 * 70; idx += 256) {
    int yy = idx / 70, xx = idx - yy * 70;
    int ih = qt * 16 + yy - 3, iw = xx - 3;
    float4 v = {0.f, 0.f, 0.f, 0.f};
    if (ih >= 0 && ih < 64 && iw >= 0 && iw < 64) {
      int wr = (ih >> 3) * 8 + (iw >> 3);
      int tok = (ih & 7) * 8 + (iw & 7);
      v = *reinterpret_cast<const float4*>(&xw[(size_t)wr * 16384 + j * 256 + tok * 4]);
    }
    sin_[0 * 1584 + yy * 72 + xx] = v.x;
    sin_[1 * 1584 + yy * 72 + xx] = v.y;
    sin_[2 * 1584 + yy * 72 + xx] = v.z;
    sin_[3 * 1584 + yy * 72 + xx] = v.w;
  }
  __syncthreads();

  float inv = g1[j] / sqrtf(v1[j] + 1e-5f);
  float shf = bb1[j] - m1[j] * inv;
  float bia = b1[j];
  float* yo = y1 + ((size_t)b * 64 + j) * HW + qt * 16 * 64;
  const float* wbase = w1 + j * 4 * 49;

  int y = threadIdx.x >> 4, x4 = (threadIdx.x & 15) * 4;
  float a0 = 0.f, a1 = 0.f, a2 = 0.f, a3 = 0.f;
  for (int i = 0; i < 4; ++i) {
    #pragma unroll
    for (int ky = 0; ky < 7; ++ky) {
      const float* row = sin_ + (i * 22 + y + ky) * 72 + x4;
      float v[10];
      #pragma unroll
      for (int q = 0; q < 10; ++q) v[q] = row[q];
      const float* wr = wbase + (i * 7 + ky) * 7;
      #pragma unroll
      for (int kx = 0; kx < 7; ++kx) {
        float wvv = wr[kx];
        a0 += v[kx] * wvv; a1 += v[kx+1] * wvv;
        a2 += v[kx+2] * wvv; a3 += v[kx+3] * wvv;
      }
    }
  }
  float4 r4;
  r4.x = fmaxf((a0 + bia) * inv + shf, 0.f);
  r4.y = fmaxf((a1 + bia) * inv + shf, 0.f);
  r4.z = fmaxf((a2 + bia) * inv + shf, 0.f);
  r4.w = fmaxf((a3 + bia) * inv + shf, 0.f);
  *reinterpret_cast<float4*>(yo + y * 64 + x4) = r4;
}

// ---------------- Kernel D: grouped conv2 + BN + sigmoid gate * x2w ----------------
__global__ __launch_bounds__(256) void kd_conv2(
    const float* __restrict__ y1, const float* __restrict__ x2w,
    const float* __restrict__ w2, const float* __restrict__ b2,
    const float* __restrict__ g2, const float* __restrict__ bb2,
    const float* __restrict__ m2, const float* __restrict__ v2,
    float* __restrict__ out)
{
  __shared__ float sin_[70 * 72];
  const int bid = blockIdx.x;
  const int wid = (bid & 7) * 256 + (bid >> 3);      // XCD-chunked (4 batches/XCD)
  int b = wid >> 6, g = wid & 63;
  const float* yin = y1 + ((size_t)b * 64 + g) * HW;
  for (int idx = threadIdx.x; idx < 70 * 70; idx += 256) {
    int yy = idx / 70, xx = idx - yy * 70;
    int ih = yy - 3, iw = xx - 3;
    float v = 0.f;
    if (ih >= 0 && ih < 64 && iw >= 0 && iw < 64) v = yin[ih * 64 + iw];
    sin_[yy * 72 + xx] = v;
  }
  __syncthreads();

  float inv[4], shf[4], bia[4];
  #pragma unroll
  for (int i = 0; i < 4; ++i) {
    int n = 4 * g + i;
    float sc = g2[n] / sqrtf(v2[n] + 1e-5f);
    inv[i] = sc; shf[i] = bb2[n] - m2[n] * sc; bia[i] = b2[n];
  }
  const float* wb = w2 + 4 * g * 49;
  const float* xw = x2w + (size_t)b * 64 * 16384;

  for (int it = 0; it < 4; ++it) {
    int s = it * 256 + threadIdx.x;
    int y = s >> 4, x4 = (s & 15) * 4;
    float acc[4][4] = {};
    #pragma unroll
    for (int ky = 0; ky < 7; ++ky) {
      const float* row = sin_ + (y + ky) * 72 + x4;
      float v[10];
      #pragma unroll
      for (int q = 0; q < 10; ++q) v[q] = row[q];
      #pragma unroll
      for (int i = 0; i < 4; ++i) {
        const float* wr = wb + i * 49 + ky * 7;
        #pragma unroll
        for (int kx = 0; kx < 7; ++kx) {
          float wvv = wr[kx];
          acc[i][0] += v[kx] * wvv; acc[i][1] += v[kx+1] * wvv;
          acc[i][2] += v[kx+2] * wvv; acc[i][3] += v[kx+3] * wvv;
        }
      }
    }
    int po = y * 64 + x4;
    // gate reads: 4 consecutive toks of plane (win, cq=g) = 64 B contiguous
    int wr_ = (y >> 3) * 8 + (x4 >> 3);
    int t0 = (y & 7) * 8 + (x4 & 7);
    const float* gp = &xw[(size_t)wr_ * 16384 + g * 256 + t0 * 4];
    float4 gx0 = *reinterpret_cast<const float4*>(gp + 0);
    float4 gx1 = *reinterpret_cast<const float4*>(gp + 4);
    float4 gx2 = *reinterpret_cast<const float4*>(gp + 8);
    float4 gx3 = *reinterpret_cast<const float4*>(gp + 12);
    #pragma unroll
    for (int i = 0; i < 4; ++i) {
      int n = 4 * g + i;
      float* op = out + ((size_t)b * 256 + n) * HW + po;
      float y0 = (acc[i][0] + bia[i]) * inv[i] + shf[i];
      float y1v = (acc[i][1] + bia[i]) * inv[i] + shf[i];
      float y2 = (acc[i][2] + bia[i]) * inv[i] + shf[i];
      float y3 = (acc[i][3] + bia[i]) * inv[i] + shf[i];
      const float* g0 = reinterpret_cast<const float*>(&gx0);
      const float* g1 = reinterpret_cast<const float*>(&gx1);
      const float* g2p = reinterpret_cast<const float*>(&gx2);
      const float* g3 = reinterpret_cast<const float*>(&gx3);
      float4 r;
      r.x = g0[i] / (1.f + __expf(-y0));
      r.y = g1[i] / (1.f + __expf(-y1v));
      r.z = g2p[i] / (1.f + __expf(-y2));
      r.w = g3[i] / (1.f + __expf(-y3));
      *reinterpret_cast<float4*>(op) = r;
    }
  }
}

extern "C" void kernel_launch(void* const* d_in, const int* in_sizes, int n_in,
                              void* d_out, int out_size, void* d_ws, size_t ws_size,
                              hipStream_t stream) {
  const float* x     = (const float*)d_in[0];
  const float* qkv_w = (const float*)d_in[1];
  const float* qkv_b = (const float*)d_in[2];
  const float* out_w = (const float*)d_in[3];
  const float* out_b = (const float*)d_in[4];
  const float* ca_w1 = (const float*)d_in[5];
  const float* ca_b1 = (const float*)d_in[6];
  const float* ca_w2 = (const float*)d_in[7];
  const float* ca_b2 = (const float*)d_in[8];
  const float* sa_w1 = (const float*)d_in[9];
  const float* sa_b1 = (const float*)d_in[10];
  const float* bn1_g = (const float*)d_in[11];
  const float* bn1_b = (const float*)d_in[12];
  const float* bn1_m = (const float*)d_in[13];
  const float* bn1_v = (const float*)d_in[14];
  const float* sa_w2 = (const float*)d_in[15];
  const float* sa_b2 = (const float*)d_in[16];
  const float* bn2_g = (const float*)d_in[17];
  const float* bn2_b = (const float*)d_in[18];
  const float* bn2_m = (const float*)d_in[19];
  const float* bn2_v = (const float*)d_in[20];

  float* outp = (float*)d_out;
  float* x2w = (float*)d_ws;                        // [win][cq][tok][quad] fp32, 128 MB
  float* y1 = x2w + (size_t)32 * 64 * 16384;        // conv1 output (b,64,64,64)

  // stash bf16 weight relayouts at the head of d_out (overwritten by kd at the end)
  u16* wqkvT = (u16*)d_out;                         // 196608
  u16* woutT = wqkvT + 768 * 256;                   // 65536
  u16* cw1t  = woutT + 256 * 256;                   // 16384
  u16* cw2t  = cw1t + 64 * 256;                     // 16384

  kprep   <<<768,  256, 0, stream>>>(qkv_w, out_w, ca_w1, ca_w2, wqkvT, woutT, cw1t, cw2t);
  kb_fused<<<2048, 256, 0, stream>>>(x, x2w, wqkvT, qkv_b, woutT, out_b, cw1t, ca_b1, cw2t, ca_b2);
  kc_conv1<<<8192, 256, 0, stream>>>(x2w, sa_w1, sa_b1, bn1_g, bn1_b, bn1_m, bn1_v, y1);
  kd_conv2<<<2048, 256, 0, stream>>>(y1, x2w, sa_w2, sa_b2, bn2_g, bn2_b, bn2_m, bn2_v, outp);
}